// Round 1
// baseline (193.066 us; speedup 1.0000x reference)
//
#include <hip/hip_runtime.h>

#define NROIS 128
#define OUTD  12
#define NVOX  (OUTD * OUTD * OUTD)
#define NCH   64

// Order-preserving encode of float32 into uint32 for atomicMax.
// f >= 0 -> bits | 0x80000000 ; f < 0 -> ~bits.
// Encoded value of any real float is > 0, so key==0 marks "empty".
__device__ __forceinline__ unsigned enc_f32(float f) {
    unsigned b = __float_as_uint(f);
    return (b & 0x80000000u) ? ~b : (b | 0x80000000u);
}

__device__ __forceinline__ float dec_key(unsigned k) {
    if (k == 0u) return 0.0f;               // empty voxel -> 0 (matches reference)
    unsigned b = (k & 0x80000000u) ? (k & 0x7fffffffu) : ~k;
    return __uint_as_float(b);
}

__global__ void __launch_bounds__(256) roi_pool_scatter(
        const float* __restrict__ rois,     // (128, 7)
        const float* __restrict__ pts,      // (P, 3)
        const float* __restrict__ feat,     // (P, 64)
        unsigned*    __restrict__ out,      // (128, 1728, 64) as encoded uint keys
        int npts)
{
    __shared__ float sroi[NROIS * 7];
    for (int i = threadIdx.x; i < NROIS * 7; i += blockDim.x) sroi[i] = rois[i];
    __syncthreads();

    int p = blockIdx.x * blockDim.x + threadIdx.x;
    if (p >= npts) return;

    float px = pts[3 * p + 0];
    float py = pts[3 * p + 1];
    float pz = pts[3 * p + 2];
    const float* fp = feat + (size_t)p * NCH;

    for (int r = 0; r < NROIS; ++r) {
        const float* R = &sroi[r * 7];
        float cx = R[0], cy = R[1], cz = R[2];
        float dx = R[3], dy = R[4], dz = R[5];
        float nrz = -R[6];

        // Replicate reference float32 op sequence exactly (no FMA contraction).
        float sx = __fsub_rn(px, cx);
        float sy = __fsub_rn(py, cy);
        float sz = __fsub_rn(pz, cz);
        float ca = cosf(nrz);
        float sa = sinf(nrz);
        float lx = __fsub_rn(__fmul_rn(sx, ca), __fmul_rn(sy, sa));
        float ly = __fadd_rn(__fmul_rn(sx, sa), __fmul_rn(sy, ca));

        float hx = __fmul_rn(dx, 0.5f);
        float hy = __fmul_rn(dy, 0.5f);
        float hz = __fmul_rn(dz, 0.5f);

        bool in_box = (lx > -hx) && (lx < hx) &&
                      (ly > -hy) && (ly < hy) &&
                      (fabsf(__fsub_rn(sz, hz)) <= hz);
        if (!in_box) continue;

        int xi = (int)floorf(__fdiv_rn(__fadd_rn(lx, hx), __fdiv_rn(dx, 12.0f)));
        int yi = (int)floorf(__fdiv_rn(__fadd_rn(ly, hy), __fdiv_rn(dy, 12.0f)));
        int zi = (int)floorf(__fdiv_rn(sz,               __fdiv_rn(dz, 12.0f)));
        xi = min(max(xi, 0), OUTD - 1);
        yi = min(max(yi, 0), OUTD - 1);
        zi = min(max(zi, 0), OUTD - 1);

        int seg = xi * (OUTD * OUTD) + yi * OUTD + zi;
        unsigned* dst = out + ((size_t)r * NVOX + (size_t)seg) * NCH;

        #pragma unroll
        for (int c = 0; c < NCH; c += 4) {
            float4 v = *reinterpret_cast<const float4*>(fp + c);
            atomicMax(dst + c + 0, enc_f32(v.x));
            atomicMax(dst + c + 1, enc_f32(v.y));
            atomicMax(dst + c + 2, enc_f32(v.z));
            atomicMax(dst + c + 3, enc_f32(v.w));
        }
    }
}

__global__ void __launch_bounds__(256) decode_keys(unsigned* __restrict__ out, int n4)
{
    int i = blockIdx.x * blockDim.x + threadIdx.x;
    if (i >= n4) return;
    uint4 k = reinterpret_cast<uint4*>(out)[i];
    float4 f;
    f.x = dec_key(k.x);
    f.y = dec_key(k.y);
    f.z = dec_key(k.z);
    f.w = dec_key(k.w);
    reinterpret_cast<float4*>(out)[i] = f;
}

extern "C" void kernel_launch(void* const* d_in, const int* in_sizes, int n_in,
                              void* d_out, int out_size, void* d_ws, size_t ws_size,
                              hipStream_t stream)
{
    const float* rois = (const float*)d_in[0];
    const float* pts  = (const float*)d_in[1];
    const float* feat = (const float*)d_in[2];
    int npts = in_sizes[1] / 3;

    // d_out is re-poisoned to 0xAA before every timed launch; zero it ourselves.
    hipMemsetAsync(d_out, 0, (size_t)out_size * sizeof(float), stream);

    int blocks = (npts + 255) / 256;
    roi_pool_scatter<<<blocks, 256, 0, stream>>>(rois, pts, feat,
                                                 (unsigned*)d_out, npts);

    int n4 = out_size / 4;
    decode_keys<<<(n4 + 255) / 256, 256, 0, stream>>>((unsigned*)d_out, n4);
}

// Round 2
// 165.924 us; speedup vs baseline: 1.1636x; 1.1636x over previous
//
#include <hip/hip_runtime.h>

#define NROIS 128
#define OUTD  12
#define NVOX  (OUTD * OUTD * OUTD)
#define NCH   64
#define RPB   16               // rois per block (grid.y = NROIS/RPB = 8)
#define RPF   12               // floats per roi in precomputed param block

// Order-preserving encode of float32 into uint32 for atomicMax.
// f >= 0 -> bits | 0x80000000 ; f < 0 -> ~bits.
// Encoded value of any real float is > 0, so key==0 marks "empty".
__device__ __forceinline__ unsigned enc_f32(float f) {
    unsigned b = __float_as_uint(f);
    return (b & 0x80000000u) ? ~b : (b | 0x80000000u);
}

__device__ __forceinline__ float dec_key(unsigned k) {
    unsigned b = (k & 0x80000000u) ? (k & 0x7fffffffu) : ~k;
    return __uint_as_float(b);
}

// Precompute per-ROI derived params once (identical float ops to the
// previous inner-loop versions, so numerics are unchanged).
__global__ void roi_prep(const float* __restrict__ rois, float* __restrict__ rp)
{
    int r = blockIdx.x * blockDim.x + threadIdx.x;
    if (r >= NROIS) return;
    float cx = rois[7 * r + 0];
    float cy = rois[7 * r + 1];
    float cz = rois[7 * r + 2];
    float dx = rois[7 * r + 3];
    float dy = rois[7 * r + 4];
    float dz = rois[7 * r + 5];
    float nrz = -rois[7 * r + 6];
    float* o = rp + r * RPF;
    o[0] = cx;
    o[1] = cy;
    o[2] = cz;
    o[3] = cosf(nrz);
    o[4] = sinf(nrz);
    o[5] = __fmul_rn(dx, 0.5f);
    o[6] = __fmul_rn(dy, 0.5f);
    o[7] = __fmul_rn(dz, 0.5f);
    o[8] = __fdiv_rn(dx, 12.0f);
    o[9] = __fdiv_rn(dy, 12.0f);
    o[10] = __fdiv_rn(dz, 12.0f);
    o[11] = 0.0f;
}

__global__ void __launch_bounds__(256) roi_pool_scatter(
        const float* __restrict__ pts,      // (P, 3)
        const float* __restrict__ feat,     // (P, 64)
        const float* __restrict__ rp,       // (128, RPF) precomputed params
        unsigned*    __restrict__ out,      // (128, 1728, 64) encoded uint keys
        int npts)
{
    __shared__ float s[RPB * RPF];
    int rbase = blockIdx.y * RPB;
    for (int i = threadIdx.x; i < RPB * RPF; i += blockDim.x)
        s[i] = rp[rbase * RPF + i];
    __syncthreads();

    int p = blockIdx.x * blockDim.x + threadIdx.x;
    if (p >= npts) return;

    float px = pts[3 * p + 0];
    float py = pts[3 * p + 1];
    float pz = pts[3 * p + 2];
    const float* fp = feat + (size_t)p * NCH;

    for (int r = 0; r < RPB; ++r) {
        const float* R = &s[r * RPF];
        // Replicate reference float32 op sequence exactly (no FMA contraction).
        float sx = __fsub_rn(px, R[0]);
        float sy = __fsub_rn(py, R[1]);
        float sz = __fsub_rn(pz, R[2]);
        float ca = R[3], sa = R[4];
        float hx = R[5], hy = R[6], hz = R[7];
        float lx = __fsub_rn(__fmul_rn(sx, ca), __fmul_rn(sy, sa));
        float ly = __fadd_rn(__fmul_rn(sx, sa), __fmul_rn(sy, ca));

        bool in_box = (lx > -hx) && (lx < hx) &&
                      (ly > -hy) && (ly < hy) &&
                      (fabsf(__fsub_rn(sz, hz)) <= hz);
        if (!in_box) continue;

        int xi = (int)floorf(__fdiv_rn(__fadd_rn(lx, hx), R[8]));
        int yi = (int)floorf(__fdiv_rn(__fadd_rn(ly, hy), R[9]));
        int zi = (int)floorf(__fdiv_rn(sz,                R[10]));
        xi = min(max(xi, 0), OUTD - 1);
        yi = min(max(yi, 0), OUTD - 1);
        zi = min(max(zi, 0), OUTD - 1);

        int seg = xi * (OUTD * OUTD) + yi * OUTD + zi;
        unsigned* dst = out + ((size_t)(rbase + r) * NVOX + (size_t)seg) * NCH;

        #pragma unroll
        for (int c = 0; c < NCH; c += 4) {
            float4 v = *reinterpret_cast<const float4*>(fp + c);
            atomicMax(dst + c + 0, enc_f32(v.x));
            atomicMax(dst + c + 1, enc_f32(v.y));
            atomicMax(dst + c + 2, enc_f32(v.z));
            atomicMax(dst + c + 3, enc_f32(v.w));
        }
    }
}

__global__ void __launch_bounds__(256) decode_keys(unsigned* __restrict__ out, int n4)
{
    int i = blockIdx.x * blockDim.x + threadIdx.x;
    if (i >= n4) return;
    uint4 k = reinterpret_cast<uint4*>(out)[i];
    // Empty voxels: key 0u == bit pattern of 0.0f -> memory already correct,
    // skip the store (saves ~95% of decode write traffic).
    if ((k.x | k.y | k.z | k.w) == 0u) return;
    float4 f;
    f.x = (k.x == 0u) ? 0.0f : dec_key(k.x);
    f.y = (k.y == 0u) ? 0.0f : dec_key(k.y);
    f.z = (k.z == 0u) ? 0.0f : dec_key(k.z);
    f.w = (k.w == 0u) ? 0.0f : dec_key(k.w);
    reinterpret_cast<float4*>(out)[i] = f;
}

extern "C" void kernel_launch(void* const* d_in, const int* in_sizes, int n_in,
                              void* d_out, int out_size, void* d_ws, size_t ws_size,
                              hipStream_t stream)
{
    const float* rois = (const float*)d_in[0];
    const float* pts  = (const float*)d_in[1];
    const float* feat = (const float*)d_in[2];
    int npts = in_sizes[1] / 3;
    float* rp = (float*)d_ws;   // 128 * RPF floats = 6 KB

    // d_out is re-poisoned to 0xAA before every timed launch; zero it ourselves.
    hipMemsetAsync(d_out, 0, (size_t)out_size * sizeof(float), stream);

    roi_prep<<<1, NROIS, 0, stream>>>(rois, rp);

    dim3 grid((npts + 255) / 256, NROIS / RPB);
    roi_pool_scatter<<<grid, 256, 0, stream>>>(pts, feat, rp,
                                               (unsigned*)d_out, npts);

    int n4 = out_size / 4;
    decode_keys<<<(n4 + 255) / 256, 256, 0, stream>>>((unsigned*)d_out, n4);
}